// Round 1
// baseline (119.663 us; speedup 1.0000x reference)
//
#include <hip/hip_runtime.h>
#include <math.h>

#define NCH   320
#define VXD   64
#define VYD   64
#define VZD   64
#define NVOX  (VXD*VYD*VZD)      // 262144
#define NTHR  256
#define VPT   4                   // voxels per thread (one float4)
#define VOXPB (NTHR*VPT)          // 1024
#define BPB   (NVOX/VOXPB)        // 256 blocks per batch
#define NB    2                   // batch

// ---- kernel 1: channel contraction + per-block stable-softmax partials ----
__global__ __launch_bounds__(NTHR) void k_corr_partial(
    const float* __restrict__ feat,
    const float* __restrict__ w,
    const float* __restrict__ bias,
    float* __restrict__ part)
{
    __shared__ float wsm[NCH];
    for (int i = threadIdx.x; i < NCH; i += NTHR) wsm[i] = w[i];
    __syncthreads();

    const int blk = blockIdx.x;                  // 0..511
    const int b   = blk / BPB;
    const int v0  = (blk % BPB) * VOXPB + threadIdx.x * VPT;

    const float4* fp = reinterpret_cast<const float4*>(feat)
                     + (size_t)b * NCH * (NVOX/4) + (v0 >> 2);

    float4 acc = make_float4(0.f, 0.f, 0.f, 0.f);
#pragma unroll 8
    for (int c = 0; c < NCH; ++c) {
        float4 f = fp[(size_t)c * (NVOX/4)];
        float wc = wsm[c];
        acc.x = fmaf(f.x, wc, acc.x);
        acc.y = fmaf(f.y, wc, acc.y);
        acc.z = fmaf(f.z, wc, acc.z);
        acc.w = fmaf(f.w, wc, acc.w);
    }
    const float bb = bias[0];
    float cv[4] = {acc.x + bb, acc.y + bb, acc.z + bb, acc.w + bb};

    // per-thread stable softmax partial over 4 voxels
    float m = fmaxf(fmaxf(cv[0], cv[1]), fmaxf(cv[2], cv[3]));
    float s = 0.f, sx = 0.f, sy = 0.f, sz = 0.f;
#pragma unroll
    for (int i = 0; i < 4; ++i) {
        const int v = v0 + i;
        const float e = __expf(cv[i] - m);
        s  += e;
        sx += e * (float)( v        & 63);
        sy += e * (float)((v >> 6)  & 63);
        sz += e * (float)( v >> 12      );
    }

    // deterministic fixed-order block tree reduce
    __shared__ float rm[NTHR], rs[NTHR], rx[NTHR], ry[NTHR], rz[NTHR];
    const int t = threadIdx.x;
    rm[t] = m; rs[t] = s; rx[t] = sx; ry[t] = sy; rz[t] = sz;
    __syncthreads();
    for (int off = NTHR/2; off > 0; off >>= 1) {
        if (t < off) {
            const float m1 = rm[t], m2 = rm[t+off];
            const float M  = fmaxf(m1, m2);
            const float e1 = __expf(m1 - M), e2 = __expf(m2 - M);
            rm[t] = M;
            rs[t] = rs[t]*e1 + rs[t+off]*e2;
            rx[t] = rx[t]*e1 + rx[t+off]*e2;
            ry[t] = ry[t]*e1 + ry[t+off]*e2;
            rz[t] = rz[t]*e1 + rz[t+off]*e2;
        }
        __syncthreads();
    }
    if (t == 0) {
        float* p = part + (size_t)blk * 5;
        p[0] = rm[0]; p[1] = rs[0]; p[2] = rx[0]; p[3] = ry[0]; p[4] = rz[0];
    }
}

// ---- kernel 2: combine 256 partials per batch, epilogue, write 39 outputs ----
__global__ __launch_bounds__(NTHR) void k_finalize(
    const float* __restrict__ part,
    const float* __restrict__ bounds,
    const int* __restrict__ zc_p,
    const int* __restrict__ yc_p,
    const int* __restrict__ xc_p,
    float* __restrict__ out)
{
    const int b = blockIdx.x;      // batch
    const int t = threadIdx.x;     // one partial per thread (BPB == NTHR)

    __shared__ float rm[NTHR], rs[NTHR], rx[NTHR], ry[NTHR], rz[NTHR];
    const float* p = part + (size_t)(b * BPB + t) * 5;
    rm[t] = p[0]; rs[t] = p[1]; rx[t] = p[2]; ry[t] = p[3]; rz[t] = p[4];
    __syncthreads();
    for (int off = NTHR/2; off > 0; off >>= 1) {
        if (t < off) {
            const float m1 = rm[t], m2 = rm[t+off];
            const float M  = fmaxf(m1, m2);
            const float e1 = __expf(m1 - M), e2 = __expf(m2 - M);
            rm[t] = M;
            rs[t] = rs[t]*e1 + rs[t+off]*e2;
            rx[t] = rx[t]*e1 + rx[t+off]*e2;
            ry[t] = ry[t]*e1 + ry[t+off]*e2;
            rz[t] = rz[t]*e1 + rz[t+off]*e2;
        }
        __syncthreads();
    }

    if (t == 0) {
        const float inv = 1.f / rs[0];
        const float xm = rx[0]*inv, ym = ry[0]*inv, zm = rz[0]*inv;

        const float XMIN = bounds[0], XMAX = bounds[1];
        const float YMIN = bounds[2], YMAX = bounds[3];
        const float ZMIN = bounds[4], ZMAX = bounds[5];
        const float Zc = (float)zc_p[0], Yc = (float)yc_p[0], Xc = (float)xc_p[0];

        const float vsx = (XMAX - XMIN) / ((float)VXD + 2.f*Xc);
        const float vsy = (YMAX - YMIN) / ((float)VYD + 2.f*Yc);
        const float vsz = (ZMAX - ZMIN) / ((float)VZD + 2.f*Zc);

        const float xcam = (xm + Xc)*vsx + XMIN;
        const float ycam = (ym + Yc)*vsy + YMIN;
        const float zcam = (zm + Zc)*vsz + ZMIN;

        if (b == 0) out[0] = 0.0f;        // total_loss = 0.0 * smooth_loss
        float* o = out + 1 + b*19;
        o[0] = 2.5f; o[1] = 1.5f; o[2] = 5.0f;          // lens
        o[3]  = 1.f; o[4]  = 0.f; o[5]  = 0.f; o[6]  = xcam;
        o[7]  = 0.f; o[8]  = 1.f; o[9]  = 0.f; o[10] = ycam;
        o[11] = 0.f; o[12] = 0.f; o[13] = 1.f; o[14] = zcam;
        o[15] = 0.f; o[16] = 0.f; o[17] = 0.f; o[18] = 1.f;
    }
}

extern "C" void kernel_launch(void* const* d_in, const int* in_sizes, int n_in,
                              void* d_out, int out_size, void* d_ws, size_t ws_size,
                              hipStream_t stream) {
    const float* feat   = (const float*)d_in[0];
    const float* w      = (const float*)d_in[1];
    const float* bias   = (const float*)d_in[2];
    const float* bounds = (const float*)d_in[3];
    const int*   zc     = (const int*)d_in[4];
    const int*   yc     = (const int*)d_in[5];
    const int*   xc     = (const int*)d_in[6];
    float* out  = (float*)d_out;
    float* part = (float*)d_ws;   // 512 blocks * 5 floats = 10 KiB

    k_corr_partial<<<NB*BPB, NTHR, 0, stream>>>(feat, w, bias, part);
    k_finalize<<<NB, NTHR, 0, stream>>>(part, bounds, zc, yc, xc, out);
}

// Round 3
// 104.159 us; speedup vs baseline: 1.1488x; 1.1488x over previous
//
#include <hip/hip_runtime.h>
#include <math.h>

#define NCH   320
#define VXD   64
#define VYD   64
#define VZD   64
#define NVOX  (VXD*VYD*VZD)      // 262144
#define NTHR  256
#define VPT   2                   // voxels per thread (one float2)
#define VOXPB (NTHR*VPT)          // 512
#define BPB   (NVOX/VOXPB)        // 512 blocks per batch
#define NB    2                   // batch

typedef float vf2 __attribute__((ext_vector_type(2)));

// ---- kernel 1: channel contraction + per-block stable-softmax partials ----
__global__ __launch_bounds__(NTHR) void k_corr_partial(
    const float* __restrict__ feat,
    const float* __restrict__ w,
    const float* __restrict__ bias,
    float* __restrict__ part)
{
    __shared__ float wsm[NCH];
    for (int i = threadIdx.x; i < NCH; i += NTHR) wsm[i] = w[i];
    __syncthreads();

    const int blk = blockIdx.x;                  // 0..1023
    const int b   = blk / BPB;
    const int v0  = (blk % BPB) * VOXPB + threadIdx.x * VPT;

    const vf2* fp = reinterpret_cast<const vf2*>(feat)
                  + (size_t)b * NCH * (NVOX/2) + (v0 >> 1);

    float ax = 0.f, ay = 0.f;
#pragma unroll 16
    for (int c = 0; c < NCH; ++c) {
        vf2 f = __builtin_nontemporal_load(fp + (size_t)c * (NVOX/2));
        const float wc = wsm[c];
        ax = fmaf(f.x, wc, ax);
        ay = fmaf(f.y, wc, ay);
    }
    const float bb = bias[0];
    const float c0 = ax + bb, c1 = ay + bb;

    // per-thread stable softmax partial over 2 voxels
    const float m  = fmaxf(c0, c1);
    const float e0 = __expf(c0 - m), e1 = __expf(c1 - m);
    const int   vA = v0, vB = v0 + 1;
    const float s  = e0 + e1;
    const float sx = e0 * (float)( vA        & 63) + e1 * (float)( vB        & 63);
    const float sy = e0 * (float)((vA >> 6)  & 63) + e1 * (float)((vB >> 6)  & 63);
    const float sz = e0 * (float)( vA >> 12      ) + e1 * (float)( vB >> 12      );

    // deterministic fixed-order block tree reduce
    __shared__ float rm[NTHR], rs[NTHR], rx[NTHR], ry[NTHR], rz[NTHR];
    const int t = threadIdx.x;
    rm[t] = m; rs[t] = s; rx[t] = sx; ry[t] = sy; rz[t] = sz;
    __syncthreads();
    for (int off = NTHR/2; off > 0; off >>= 1) {
        if (t < off) {
            const float m1 = rm[t], m2 = rm[t+off];
            const float M  = fmaxf(m1, m2);
            const float f1 = __expf(m1 - M), f2 = __expf(m2 - M);
            rm[t] = M;
            rs[t] = rs[t]*f1 + rs[t+off]*f2;
            rx[t] = rx[t]*f1 + rx[t+off]*f2;
            ry[t] = ry[t]*f1 + ry[t+off]*f2;
            rz[t] = rz[t]*f1 + rz[t+off]*f2;
        }
        __syncthreads();
    }
    if (t == 0) {
        float* p = part + (size_t)blk * 5;
        p[0] = rm[0]; p[1] = rs[0]; p[2] = rx[0]; p[3] = ry[0]; p[4] = rz[0];
    }
}

// ---- kernel 2: combine BPB partials per batch, epilogue, write 39 outputs ----
__global__ __launch_bounds__(NTHR) void k_finalize(
    const float* __restrict__ part,
    const float* __restrict__ bounds,
    const int* __restrict__ zc_p,
    const int* __restrict__ yc_p,
    const int* __restrict__ xc_p,
    float* __restrict__ out)
{
    const int b = blockIdx.x;      // batch
    const int t = threadIdx.x;

    __shared__ float rm[NTHR], rs[NTHR], rx[NTHR], ry[NTHR], rz[NTHR];

    // pre-merge the two partials this thread owns (BPB == 2*NTHR)
    const float* pa = part + (size_t)(b * BPB + t) * 5;
    const float* pb = part + (size_t)(b * BPB + t + NTHR) * 5;
    {
        const float m1 = pa[0], m2 = pb[0];
        const float M  = fmaxf(m1, m2);
        const float f1 = __expf(m1 - M), f2 = __expf(m2 - M);
        rm[t] = M;
        rs[t] = pa[1]*f1 + pb[1]*f2;
        rx[t] = pa[2]*f1 + pb[2]*f2;
        ry[t] = pa[3]*f1 + pb[3]*f2;
        rz[t] = pa[4]*f1 + pb[4]*f2;
    }
    __syncthreads();
    for (int off = NTHR/2; off > 0; off >>= 1) {
        if (t < off) {
            const float m1 = rm[t], m2 = rm[t+off];
            const float M  = fmaxf(m1, m2);
            const float f1 = __expf(m1 - M), f2 = __expf(m2 - M);
            rm[t] = M;
            rs[t] = rs[t]*f1 + rs[t+off]*f2;
            rx[t] = rx[t]*f1 + rx[t+off]*f2;
            ry[t] = ry[t]*f1 + ry[t+off]*f2;
            rz[t] = rz[t]*f1 + rz[t+off]*f2;
        }
        __syncthreads();
    }

    if (t == 0) {
        const float inv = 1.f / rs[0];
        const float xm = rx[0]*inv, ym = ry[0]*inv, zm = rz[0]*inv;

        const float XMIN = bounds[0], XMAX = bounds[1];
        const float YMIN = bounds[2], YMAX = bounds[3];
        const float ZMIN = bounds[4], ZMAX = bounds[5];
        const float Zc = (float)zc_p[0], Yc = (float)yc_p[0], Xc = (float)xc_p[0];

        const float vsx = (XMAX - XMIN) / ((float)VXD + 2.f*Xc);
        const float vsy = (YMAX - YMIN) / ((float)VYD + 2.f*Yc);
        const float vsz = (ZMAX - ZMIN) / ((float)VZD + 2.f*Zc);

        const float xcam = (xm + Xc)*vsx + XMIN;
        const float ycam = (ym + Yc)*vsy + YMIN;
        const float zcam = (zm + Zc)*vsz + ZMIN;

        if (b == 0) out[0] = 0.0f;        // total_loss = 0.0 * smooth_loss
        float* o = out + 1 + b*19;
        o[0] = 2.5f; o[1] = 1.5f; o[2] = 5.0f;          // lens
        o[3]  = 1.f; o[4]  = 0.f; o[5]  = 0.f; o[6]  = xcam;
        o[7]  = 0.f; o[8]  = 1.f; o[9]  = 0.f; o[10] = ycam;
        o[11] = 0.f; o[12] = 0.f; o[13] = 1.f; o[14] = zcam;
        o[15] = 0.f; o[16] = 0.f; o[17] = 0.f; o[18] = 1.f;
    }
}

extern "C" void kernel_launch(void* const* d_in, const int* in_sizes, int n_in,
                              void* d_out, int out_size, void* d_ws, size_t ws_size,
                              hipStream_t stream) {
    const float* feat   = (const float*)d_in[0];
    const float* w      = (const float*)d_in[1];
    const float* bias   = (const float*)d_in[2];
    const float* bounds = (const float*)d_in[3];
    const int*   zc     = (const int*)d_in[4];
    const int*   yc     = (const int*)d_in[5];
    const int*   xc     = (const int*)d_in[6];
    float* out  = (float*)d_out;
    float* part = (float*)d_ws;   // 1024 blocks * 5 floats = 20 KiB

    k_corr_partial<<<NB*BPB, NTHR, 0, stream>>>(feat, w, bias, part);
    k_finalize<<<NB, NTHR, 0, stream>>>(part, bounds, zc, yc, xc, out);
}